// Round 14
// baseline (135.128 us; speedup 1.0000x reference)
//
#include <hip/hip_runtime.h>

typedef __attribute__((ext_vector_type(8))) short short8;
typedef __attribute__((ext_vector_type(4))) float f32x4;

__device__ __forceinline__ float bf2f(unsigned short u) {
    union { unsigned int i; float f; } v; v.i = ((unsigned int)u) << 16; return v.f;
}
__device__ __forceinline__ unsigned short f2bf(float f) {
    union { float f; unsigned int i; } v; v.f = f;
    unsigned int r = v.i + 0x7fffu + ((v.i >> 16) & 1u);  // RNE
    return (unsigned short)(r >> 16);
}
__device__ __forceinline__ void gload16(const unsigned short* g, unsigned short* l) {
    __builtin_amdgcn_global_load_lds(
        (const __attribute__((address_space(1))) unsigned int*)g,
        (__attribute__((address_space(3))) unsigned int*)l, 16, 0, 0);
}

#define VM(n) asm volatile("s_waitcnt vmcnt(%0)" :: "i"(n) : "memory")
#define SBAR() __builtin_amdgcn_s_barrier()
#define SCHED0() __builtin_amdgcn_sched_barrier(0)

// ---------------------------------------------------------------------------
// R10-verified GEMM (measured optimum of this structure family):
// 128x128 tile, BK=64, 8 waves (64x32/wave), 64KB LDS -> 2 blocks/CU,
// counted vmcnt(4), XOR swizzle (measured 0 bank conflicts).
// C[M][1024](bf16) = A[M][K](bf16) @ Bt[1024][K]^T(bf16) + bias.
// MODE 0: merged shared transform (M=16384, sel by row half, out pitch 2048).
// MODE 1: language-selected Wg1 stack (M=8192, out pitch 1024).
// ---------------------------------------------------------------------------
template<int K, int MODE>
__global__ __launch_bounds__(512, 4) void gemm_w8(
    const unsigned short* __restrict__ A,
    const unsigned short* __restrict__ Bta,
    const unsigned short* __restrict__ Btb,
    const float* __restrict__ biasa,
    const float* __restrict__ biasb,
    unsigned short* __restrict__ Cb,
    const int* __restrict__ lang)
{
    __shared__ __align__(16) unsigned short As0[128][64], Bs0[128][64];
    __shared__ __align__(16) unsigned short As1[128][64], Bs1[128][64];

    const int t = threadIdx.x;
    const int nx = gridDim.x;                       // 8
    const int bid = blockIdx.y * nx + blockIdx.x;
    const int cpx = (nx * gridDim.y) >> 3;
    const int swz = (bid & 7) * cpx + (bid >> 3);
    const int gm0 = (swz >> 3) * 128;
    const int gn0 = (swz & 7) * 128;

    const unsigned short* Bt;
    const float* bias;
    int sel = 0;
    if (MODE == 0) {
        sel = gm0 >> 13;
        Bt = sel ? Btb : Bta;
        bias = sel ? biasb : biasa;
    } else {
        const int l = lang[gm0 >> 9];
        Bt = Bta + (size_t)l * ((size_t)K * 1024);
        bias = biasa + l * 1024;
    }

    const int lane = t & 63;
    const int w = t >> 6;
    const int wm = w >> 2, wn = w & 3;              // 2M x 4N waves, 64x32 each
    const int fr = lane & 15, g4 = lane >> 4, f7 = lane & 7;
    const int csw0 = ((0 + g4) ^ f7) * 8;
    const int csw1 = ((4 + g4) ^ f7) * 8;

    // staging: lane-linear LDS dest (byte offset t*16), pre-swizzled global col
    const int srow = t >> 3;                        // 0..63
    const int swcol = ((t & 7) ^ (srow & 7)) * 8;
    const int lcol = (t & 7) * 8;
    const unsigned short* ag = A  + (size_t)(gm0 + srow) * K + swcol;
    const unsigned short* bg = Bt + (size_t)(gn0 + srow) * K + swcol;

    f32x4 acc[4][2];
#pragma unroll
    for (int m = 0; m < 4; ++m)
#pragma unroll
        for (int n = 0; n < 2; ++n)
            acc[m][n] = (f32x4){0.f, 0.f, 0.f, 0.f};

    auto stage = [&](unsigned short (*As)[64], unsigned short (*Bs)[64], int k0) {
#pragma unroll
        for (int i = 0; i < 2; ++i) {
            gload16(ag + (size_t)(i * 64) * K + k0, &As[i * 64 + srow][lcol]);
            gload16(bg + (size_t)(i * 64) * K + k0, &Bs[i * 64 + srow][lcol]);
        }
    };
    auto compute = [&](const unsigned short (*As)[64], const unsigned short (*Bs)[64]) {
        short8 a0[4], b0[2];
#pragma unroll
        for (int m = 0; m < 4; ++m) a0[m] = *(const short8*)&As[wm * 64 + m * 16 + fr][csw0];
#pragma unroll
        for (int n = 0; n < 2; ++n) b0[n] = *(const short8*)&Bs[wn * 32 + n * 16 + fr][csw0];
        __builtin_amdgcn_s_setprio(1);
#pragma unroll
        for (int m = 0; m < 4; ++m)
#pragma unroll
            for (int n = 0; n < 2; ++n)
                acc[m][n] = __builtin_amdgcn_mfma_f32_16x16x32_bf16(a0[m], b0[n], acc[m][n], 0, 0, 0);
        __builtin_amdgcn_s_setprio(0);
#pragma unroll
        for (int m = 0; m < 4; ++m) a0[m] = *(const short8*)&As[wm * 64 + m * 16 + fr][csw1];
#pragma unroll
        for (int n = 0; n < 2; ++n) b0[n] = *(const short8*)&Bs[wn * 32 + n * 16 + fr][csw1];
        __builtin_amdgcn_s_setprio(1);
#pragma unroll
        for (int m = 0; m < 4; ++m)
#pragma unroll
            for (int n = 0; n < 2; ++n)
                acc[m][n] = __builtin_amdgcn_mfma_f32_16x16x32_bf16(a0[m], b0[n], acc[m][n], 0, 0, 0);
        __builtin_amdgcn_s_setprio(0);
    };

    constexpr int NT = K / 64;           // even (12 or 32)
    stage(As0, Bs0, 0);
    stage(As1, Bs1, 64);

    for (int tt = 0; tt < NT; tt += 2) {
        VM(4);
        SBAR();
        asm volatile("" ::: "memory");
        SCHED0();
        compute(As0, Bs0);
        SCHED0();
        SBAR();
        if (tt + 2 < NT) stage(As0, Bs0, (tt + 2) * 64);
        if (tt + 2 < NT) VM(4); else VM(0);
        SBAR();
        asm volatile("" ::: "memory");
        SCHED0();
        compute(As1, Bs1);
        SCHED0();
        SBAR();
        if (tt + 3 < NT) stage(As1, Bs1, (tt + 3) * 64);
    }

    // epilogue: D mapping col=lane&15, row=(lane>>4)*4+reg; bf16 store
    const int fq = lane >> 4;
    const size_t pitch  = (MODE == 0) ? 2048 : 1024;
    const size_t coloff = (MODE == 0) ? (size_t)sel * 1024 : 0;
    const int rbase = (MODE == 0) ? (gm0 & 8191) : gm0;
#pragma unroll
    for (int n = 0; n < 2; ++n) {
        const int col = gn0 + wn * 32 + n * 16 + fr;
        const float bv = bias[col];
#pragma unroll
        for (int m = 0; m < 4; ++m) {
            const int row0 = rbase + wm * 64 + m * 16 + fq * 4;
#pragma unroll
            for (int r = 0; r < 4; ++r)
                Cb[(size_t)(row0 + r) * pitch + coloff + col] = f2bf(acc[m][n][r] + bv);
        }
    }
}

// ---- weight transposes: 128x128 f32 tiles, 512B loads / 256B stores ----
__device__ __forceinline__ void wt_tile128(
    const float* W, unsigned short* Wt, int K, int N, int bx, int by,
    float (*tile)[129], int t)
{
    const int n0 = bx * 128, k0 = by * 128;
    const int lr = t >> 5, lc = (t & 31) * 4;       // 8 rows/pass, 512B/row
#pragma unroll
    for (int p = 0; p < 16; ++p) {
        const int r = p * 8 + lr;
        *(float4*)&tile[r][lc] = *(const float4*)&W[(size_t)(k0 + r) * N + n0 + lc];
    }
    __syncthreads();
    const int u = t & 15, nn = t >> 4;              // 16 k-slots x 16 n/pass
#pragma unroll
    for (int p = 0; p < 8; ++p) {
        const int n = p * 16 + nn;
        short8 s;
#pragma unroll
        for (int j = 0; j < 8; ++j) s[j] = (short)f2bf(tile[u * 8 + j][n]);
        *(short8*)&Wt[(size_t)(n0 + n) * K + k0 + u * 8] = s;  // 256B/16 lanes
    }
}

__global__ __launch_bounds__(256) void wt_all(
    const float* __restrict__ W_ner, unsigned short* __restrict__ W_nert,
    const float* __restrict__ W_top, unsigned short* __restrict__ W_topt,
    const float* __restrict__ Wg1,   unsigned short* __restrict__ Wg1t)
{
    __shared__ float tile[128][129];
    int b = blockIdx.x;
    const int t = threadIdx.x;
    if (b < 48)  { wt_tile128(W_ner, W_nert, 768, 1024, b % 8, b / 8, tile, t); return; }
    b -= 48;
    if (b < 48)  { wt_tile128(W_top, W_topt, 768, 1024, b % 8, b / 8, tile, t); return; }
    b -= 48;
    const int z = b / 128, r = b % 128;
    wt_tile128(Wg1 + (size_t)z * 2097152, Wg1t + (size_t)z * 2097152,
               2048, 1024, r % 8, r / 8, tile, t);
}

// f32 -> bf16 elementwise (2048 elems / block); ner then top, concatenated on M
__global__ __launch_bounds__(256) void conv_bf16(
    const float* __restrict__ ner, const float* __restrict__ top,
    unsigned short* __restrict__ actb)
{
    const int b = blockIdx.x;
    const float* in = (b < 3072) ? ner : top;
    unsigned short* out = actb + ((b < 3072) ? 0 : 6291456);
    const int bb = (b < 3072) ? b : (b - 3072);
    const size_t i = ((size_t)bb * 256 + threadIdx.x) * 8;
    const float4 a = ((const float4*)(in + i))[0];
    const float4 c = ((const float4*)(in + i))[1];
    ushort4 u, v;
    u.x = f2bf(a.x); u.y = f2bf(a.y); u.z = f2bf(a.z); u.w = f2bf(a.w);
    v.x = f2bf(c.x); v.y = f2bf(c.y); v.z = f2bf(c.z); v.w = f2bf(c.w);
    *(ushort4*)(out + i)     = u;
    *(ushort4*)(out + i + 4) = v;
}

// in-place LN(1024)+ReLU on combined halves (bf16). grid 16384: r=b>>1, half=b&1
__global__ __launch_bounds__(256) void ln_relu_c(
    unsigned short* __restrict__ comb,
    const float* __restrict__ gn, const float* __restrict__ bn,
    const float* __restrict__ gt, const float* __restrict__ btp)
{
    const int b = blockIdx.x, t = threadIdx.x;
    const int r = b >> 1, half = b & 1;
    unsigned short* p = comb + (size_t)r * 2048 + half * 1024 + t * 4;
    ushort4 u = *(const ushort4*)p;
    const float x0 = bf2f(u.x), x1 = bf2f(u.y), x2 = bf2f(u.z), x3 = bf2f(u.w);
    float s1 = x0 + x1 + x2 + x3;
    float s2 = x0 * x0 + x1 * x1 + x2 * x2 + x3 * x3;
#pragma unroll
    for (int off = 32; off > 0; off >>= 1) {
        s1 += __shfl_down(s1, off);
        s2 += __shfl_down(s2, off);
    }
    __shared__ float red[8];
    const int wid = t >> 6;
    if ((t & 63) == 0) { red[wid] = s1; red[4 + wid] = s2; }
    __syncthreads();
    s1 = red[0] + red[1] + red[2] + red[3];
    s2 = red[4] + red[5] + red[6] + red[7];
    const float mean = s1 * (1.0f / 1024.0f);
    const float var = fmaxf(s2 * (1.0f / 1024.0f) - mean * mean, 0.0f);
    const float rstd = rsqrtf(var + 1e-5f);
    const float* G  = half ? gt : gn;
    const float* Be = half ? btp : bn;
    const float4 g  = ((const float4*)G)[t];
    const float4 be = ((const float4*)Be)[t];
    u.x = f2bf(fmaxf((x0 - mean) * rstd * g.x + be.x, 0.0f));
    u.y = f2bf(fmaxf((x1 - mean) * rstd * g.y + be.y, 0.0f));
    u.z = f2bf(fmaxf((x2 - mean) * rstd * g.z + be.z, 0.0f));
    u.w = f2bf(fmaxf((x3 - mean) * rstd * g.w + be.w, 0.0f));
    *(ushort4*)p = u;
}

// Fused: LN(1024)+ReLU on preln row (lang gamma/beta) -> gate dots -> sigmoid
// -> scale combined halves -> f32 outputs. One block per row.
__global__ __launch_bounds__(256) void ln_gate(
    const unsigned short* __restrict__ preln, const unsigned short* __restrict__ comb,
    const float* __restrict__ gg, const float* __restrict__ bgb,
    const float* __restrict__ Wg2, const float* __restrict__ bg2,
    const int* __restrict__ lang,
    float* __restrict__ outN, float* __restrict__ outT)
{
    const int r = blockIdx.x, t = threadIdx.x;
    const int l = lang[r >> 9];
    const ushort4 u = *(const ushort4*)(preln + (size_t)r * 1024 + t * 4);
    const float x0 = bf2f(u.x), x1 = bf2f(u.y), x2 = bf2f(u.z), x3 = bf2f(u.w);
    float s1 = x0 + x1 + x2 + x3;
    float s2 = x0 * x0 + x1 * x1 + x2 * x2 + x3 * x3;
#pragma unroll
    for (int off = 32; off > 0; off >>= 1) {
        s1 += __shfl_down(s1, off);
        s2 += __shfl_down(s2, off);
    }
    __shared__ float red[8];
    const int wid = t >> 6;
    if ((t & 63) == 0) { red[wid] = s1; red[4 + wid] = s2; }
    __syncthreads();
    s1 = red[0] + red[1] + red[2] + red[3];
    s2 = red[4] + red[5] + red[6] + red[7];
    const float mean = s1 * (1.0f / 1024.0f);
    const float var = fmaxf(s2 * (1.0f / 1024.0f) - mean * mean, 0.0f);
    const float rstd = rsqrtf(var + 1e-5f);
    const float4 g  = ((const float4*)(gg + l * 1024))[t];
    const float4 be = ((const float4*)(bgb + l * 1024))[t];
    const float h0 = fmaxf((x0 - mean) * rstd * g.x + be.x, 0.0f);
    const float h1 = fmaxf((x1 - mean) * rstd * g.y + be.y, 0.0f);
    const float h2 = fmaxf((x2 - mean) * rstd * g.z + be.z, 0.0f);
    const float h3 = fmaxf((x3 - mean) * rstd * g.w + be.w, 0.0f);
    const float4* W = (const float4*)(Wg2 + (size_t)l * 2048);
    const float4 wa = W[t * 2], wb = W[t * 2 + 1];
    float d0 = h0 * wa.x + h1 * wa.z + h2 * wb.x + h3 * wb.z;
    float d1 = h0 * wa.y + h1 * wa.w + h2 * wb.y + h3 * wb.w;
#pragma unroll
    for (int off = 32; off > 0; off >>= 1) {
        d0 += __shfl_down(d0, off);
        d1 += __shfl_down(d1, off);
    }
    __syncthreads();
    if ((t & 63) == 0) { red[wid] = d0; red[4 + wid] = d1; }
    __syncthreads();
    d0 = red[0] + red[1] + red[2] + red[3] + bg2[l * 2 + 0];
    d1 = red[4] + red[5] + red[6] + red[7] + bg2[l * 2 + 1];
    const float g0 = 1.0f / (1.0f + __expf(-d0));
    const float g1 = 1.0f / (1.0f + __expf(-d1));
    const ushort4 cn = *(const ushort4*)(comb + (size_t)r * 2048 + t * 4);
    const ushort4 ct = *(const ushort4*)(comb + (size_t)r * 2048 + 1024 + t * 4);
    float4 a, b;
    a.x = bf2f(cn.x) * g0; a.y = bf2f(cn.y) * g0; a.z = bf2f(cn.z) * g0; a.w = bf2f(cn.w) * g0;
    b.x = bf2f(ct.x) * g1; b.y = bf2f(ct.y) * g1; b.z = bf2f(ct.z) * g1; b.w = bf2f(ct.w) * g1;
    ((float4*)(outN + (size_t)r * 1024))[t] = a;
    ((float4*)(outT + (size_t)r * 1024))[t] = b;
}

extern "C" void kernel_launch(void* const* d_in, const int* in_sizes, int n_in,
                              void* d_out, int out_size, void* d_ws, size_t ws_size,
                              hipStream_t stream)
{
    const float* ner    = (const float*)d_in[0];
    const float* top    = (const float*)d_in[1];
    const int*   lang   = (const int*)d_in[2];
    const float* W_ner  = (const float*)d_in[3];
    const float* b_ner  = (const float*)d_in[4];
    const float* g_ner  = (const float*)d_in[5];
    const float* be_ner = (const float*)d_in[6];
    const float* W_top  = (const float*)d_in[7];
    const float* b_top  = (const float*)d_in[8];
    const float* g_top  = (const float*)d_in[9];
    const float* be_top = (const float*)d_in[10];
    const float* Wg1    = (const float*)d_in[11];
    const float* bg1    = (const float*)d_in[12];
    const float* gg     = (const float*)d_in[13];
    const float* bgb    = (const float*)d_in[14];
    const float* Wg2    = (const float*)d_in[15];
    const float* bg2    = (const float*)d_in[16];

    float* out  = (float*)d_out;
    float* outN = out;
    float* outT = out + 8388608;

    // ws layout: combined 32MB | actb 24MB (later preln2) | Wg1t 20MB
    char* ws = (char*)d_ws;
    unsigned short* combined = (unsigned short*)ws;
    unsigned short* actb     = (unsigned short*)(ws + 33554432);
    unsigned short* preln2   = (unsigned short*)(ws + 33554432);  // overlays actb (dead)
    unsigned short* Wg1t     = (unsigned short*)(ws + 58720256);
    unsigned short* W_nert   = (unsigned short*)outT;             // d_out scratch
    unsigned short* W_topt   = W_nert + 786432;

    // prep: streaming conv (full occupancy) + 128x128 weight transposes
    conv_bf16<<<6144, 256, 0, stream>>>(ner, top, actb);
    wt_all<<<736, 256, 0, stream>>>(W_ner, W_nert, W_top, W_topt, Wg1, Wg1t);

    // merged shared-transform GEMM: [16384][768] -> combined pre-LN bf16
    gemm_w8<768, 0><<<dim3(8, 128), 512, 0, stream>>>(
        actb, W_nert, W_topt, b_ner, b_top, combined, nullptr);
    ln_relu_c<<<16384, 256, 0, stream>>>(combined, g_ner, be_ner, g_top, be_top);

    // gate GEMM (language-selected): combined @ Wg1t[l] -> preln2 bf16
    gemm_w8<2048, 1><<<dim3(8, 64), 512, 0, stream>>>(
        combined, Wg1t, nullptr, bg1, nullptr, preln2, lang);

    // fused LN2 + gate dots + sigmoid + output scaling
    ln_gate<<<8192, 256, 0, stream>>>(preln2, combined, gg, bgb, Wg2, bg2, lang, outN, outT);
}

// Round 15
// 130.202 us; speedup vs baseline: 1.0378x; 1.0378x over previous
//
#include <hip/hip_runtime.h>

typedef __attribute__((ext_vector_type(8))) short short8;
typedef __attribute__((ext_vector_type(4))) float f32x4;

__device__ __forceinline__ float bf2f(unsigned short u) {
    union { unsigned int i; float f; } v; v.i = ((unsigned int)u) << 16; return v.f;
}
__device__ __forceinline__ unsigned short f2bf(float f) {
    union { float f; unsigned int i; } v; v.f = f;
    unsigned int r = v.i + 0x7fffu + ((v.i >> 16) & 1u);  // RNE
    return (unsigned short)(r >> 16);
}
__device__ __forceinline__ void gload16(const unsigned short* g, unsigned short* l) {
    __builtin_amdgcn_global_load_lds(
        (const __attribute__((address_space(1))) unsigned int*)g,
        (__attribute__((address_space(3))) unsigned int*)l, 16, 0, 0);
}

#define VM(n) asm volatile("s_waitcnt vmcnt(%0)" :: "i"(n) : "memory")
#define SBAR() __builtin_amdgcn_s_barrier()
#define SCHED0() __builtin_amdgcn_sched_barrier(0)

// ---------------------------------------------------------------------------
// R10/R13-verified GEMM (measured optimum of this structure family):
// 128x128 tile, BK=64, 8 waves (64x32/wave), 64KB LDS -> 2 blocks/CU,
// counted vmcnt(4), XOR swizzle (measured 0 bank conflicts).
// C[M][1024](bf16) = A[M][K](bf16) @ Bt[1024][K]^T(bf16) + bias.
// MODE 0: merged shared transform (M=16384, sel by row half, out pitch 2048).
// MODE 1: language-selected Wg1 stack (M=8192, out pitch 1024).
// ---------------------------------------------------------------------------
template<int K, int MODE>
__global__ __launch_bounds__(512, 4) void gemm_w8(
    const unsigned short* __restrict__ A,
    const unsigned short* __restrict__ Bta,
    const unsigned short* __restrict__ Btb,
    const float* __restrict__ biasa,
    const float* __restrict__ biasb,
    unsigned short* __restrict__ Cb,
    const int* __restrict__ lang)
{
    __shared__ __align__(16) unsigned short As0[128][64], Bs0[128][64];
    __shared__ __align__(16) unsigned short As1[128][64], Bs1[128][64];

    const int t = threadIdx.x;
    const int nx = gridDim.x;                       // 8
    const int bid = blockIdx.y * nx + blockIdx.x;
    const int cpx = (nx * gridDim.y) >> 3;
    const int swz = (bid & 7) * cpx + (bid >> 3);
    const int gm0 = (swz >> 3) * 128;
    const int gn0 = (swz & 7) * 128;

    const unsigned short* Bt;
    const float* bias;
    int sel = 0;
    if (MODE == 0) {
        sel = gm0 >> 13;
        Bt = sel ? Btb : Bta;
        bias = sel ? biasb : biasa;
    } else {
        const int l = lang[gm0 >> 9];
        Bt = Bta + (size_t)l * ((size_t)K * 1024);
        bias = biasa + l * 1024;
    }

    const int lane = t & 63;
    const int w = t >> 6;
    const int wm = w >> 2, wn = w & 3;              // 2M x 4N waves, 64x32 each
    const int fr = lane & 15, g4 = lane >> 4, f7 = lane & 7;
    const int csw0 = ((0 + g4) ^ f7) * 8;
    const int csw1 = ((4 + g4) ^ f7) * 8;

    // staging: lane-linear LDS dest (byte offset t*16), pre-swizzled global col
    const int srow = t >> 3;                        // 0..63
    const int swcol = ((t & 7) ^ (srow & 7)) * 8;
    const int lcol = (t & 7) * 8;
    const unsigned short* ag = A  + (size_t)(gm0 + srow) * K + swcol;
    const unsigned short* bg = Bt + (size_t)(gn0 + srow) * K + swcol;

    f32x4 acc[4][2];
#pragma unroll
    for (int m = 0; m < 4; ++m)
#pragma unroll
        for (int n = 0; n < 2; ++n)
            acc[m][n] = (f32x4){0.f, 0.f, 0.f, 0.f};

    auto stage = [&](unsigned short (*As)[64], unsigned short (*Bs)[64], int k0) {
#pragma unroll
        for (int i = 0; i < 2; ++i) {
            gload16(ag + (size_t)(i * 64) * K + k0, &As[i * 64 + srow][lcol]);
            gload16(bg + (size_t)(i * 64) * K + k0, &Bs[i * 64 + srow][lcol]);
        }
    };
    auto compute = [&](const unsigned short (*As)[64], const unsigned short (*Bs)[64]) {
        short8 a0[4], b0[2];
#pragma unroll
        for (int m = 0; m < 4; ++m) a0[m] = *(const short8*)&As[wm * 64 + m * 16 + fr][csw0];
#pragma unroll
        for (int n = 0; n < 2; ++n) b0[n] = *(const short8*)&Bs[wn * 32 + n * 16 + fr][csw0];
        __builtin_amdgcn_s_setprio(1);
#pragma unroll
        for (int m = 0; m < 4; ++m)
#pragma unroll
            for (int n = 0; n < 2; ++n)
                acc[m][n] = __builtin_amdgcn_mfma_f32_16x16x32_bf16(a0[m], b0[n], acc[m][n], 0, 0, 0);
        __builtin_amdgcn_s_setprio(0);
#pragma unroll
        for (int m = 0; m < 4; ++m) a0[m] = *(const short8*)&As[wm * 64 + m * 16 + fr][csw1];
#pragma unroll
        for (int n = 0; n < 2; ++n) b0[n] = *(const short8*)&Bs[wn * 32 + n * 16 + fr][csw1];
        __builtin_amdgcn_s_setprio(1);
#pragma unroll
        for (int m = 0; m < 4; ++m)
#pragma unroll
            for (int n = 0; n < 2; ++n)
                acc[m][n] = __builtin_amdgcn_mfma_f32_16x16x32_bf16(a0[m], b0[n], acc[m][n], 0, 0, 0);
        __builtin_amdgcn_s_setprio(0);
    };

    constexpr int NT = K / 64;           // even (12 or 32)
    stage(As0, Bs0, 0);
    stage(As1, Bs1, 64);

    for (int tt = 0; tt < NT; tt += 2) {
        VM(4);
        SBAR();
        asm volatile("" ::: "memory");
        SCHED0();
        compute(As0, Bs0);
        SCHED0();
        SBAR();
        if (tt + 2 < NT) stage(As0, Bs0, (tt + 2) * 64);
        if (tt + 2 < NT) VM(4); else VM(0);
        SBAR();
        asm volatile("" ::: "memory");
        SCHED0();
        compute(As1, Bs1);
        SCHED0();
        SBAR();
        if (tt + 3 < NT) stage(As1, Bs1, (tt + 3) * 64);
    }

    // epilogue: D mapping col=lane&15, row=(lane>>4)*4+reg; bf16 store
    const int fq = lane >> 4;
    const size_t pitch  = (MODE == 0) ? 2048 : 1024;
    const size_t coloff = (MODE == 0) ? (size_t)sel * 1024 : 0;
    const int rbase = (MODE == 0) ? (gm0 & 8191) : gm0;
#pragma unroll
    for (int n = 0; n < 2; ++n) {
        const int col = gn0 + wn * 32 + n * 16 + fr;
        const float bv = bias[col];
#pragma unroll
        for (int m = 0; m < 4; ++m) {
            const int row0 = rbase + wm * 64 + m * 16 + fq * 4;
#pragma unroll
            for (int r = 0; r < 4; ++r)
                Cb[(size_t)(row0 + r) * pitch + coloff + col] = f2bf(acc[m][n][r] + bv);
        }
    }
}

// ---- fused prep: weight transposes (64x64 tiles, coalesced 16B stores) + convs ----
__device__ __forceinline__ void wt_tile64(
    const float* W, unsigned short* Wt, int K, int N, int bx, int by,
    float (*tile)[65], int t)
{
    const int n0 = bx * 64, k0 = by * 64;
    const int x = t & 15, y = t >> 4;               // x: n-quad, y: k-row group
#pragma unroll
    for (int i = 0; i < 4; ++i) {
        const float4 v = *(const float4*)&W[(size_t)(k0 + y + 16 * i) * N + n0 + x * 4];
        *(float4*)&tile[y + 16 * i][x * 4] = v;
    }
    __syncthreads();
    const int u = t & 7, vr = t >> 3;               // u: k-slot of 8, vr: n-row 0..31
#pragma unroll
    for (int i = 0; i < 2; ++i) {
        const int n = vr + 32 * i;
        short8 s;
#pragma unroll
        for (int j = 0; j < 8; ++j) s[j] = (short)f2bf(tile[u * 8 + j][n]);
        *(short8*)&Wt[(size_t)(n0 + n) * K + k0 + u * 8] = s;
    }
}
__device__ __forceinline__ void conv_chunk(
    const float* in, unsigned short* out, int b, int t)
{
    const size_t i = ((size_t)b * 256 + t) * 8;
    const float4 a = ((const float4*)(in + i))[0];
    const float4 c = ((const float4*)(in + i))[1];
    ushort4 u, v;
    u.x = f2bf(a.x); u.y = f2bf(a.y); u.z = f2bf(a.z); u.w = f2bf(a.w);
    v.x = f2bf(c.x); v.y = f2bf(c.y); v.z = f2bf(c.z); v.w = f2bf(c.w);
    *(ushort4*)(out + i)     = u;
    *(ushort4*)(out + i + 4) = v;
}

__global__ __launch_bounds__(256) void prep_all(
    const float* __restrict__ W_ner, unsigned short* __restrict__ W_nert,
    const float* __restrict__ W_top, unsigned short* __restrict__ W_topt,
    const float* __restrict__ Wg1,   unsigned short* __restrict__ Wg1t,
    const float* __restrict__ ner,   const float* __restrict__ top,
    unsigned short* __restrict__ actb)
{
    __shared__ float tile[64][65];
    int b = blockIdx.x;
    const int t = threadIdx.x;
    if (b < 192)  { wt_tile64(W_ner, W_nert, 768, 1024, b % 16, b / 16, tile, t); return; }
    b -= 192;
    if (b < 192)  { wt_tile64(W_top, W_topt, 768, 1024, b % 16, b / 16, tile, t); return; }
    b -= 192;
    if (b < 2560) {
        const int z = b / 512, r = b % 512;
        wt_tile64(Wg1 + (size_t)z * 2097152, Wg1t + (size_t)z * 2097152,
                  2048, 1024, r % 16, r / 16, tile, t);
        return;
    }
    b -= 2560;
    if (b < 3072) { conv_chunk(ner, actb, b, t); return; }
    b -= 3072;
    conv_chunk(top, actb + 6291456, b, t);
}

// in-place LN(1024)+ReLU on combined halves (bf16). grid 16384: r=b>>1, half=b&1
__global__ __launch_bounds__(256) void ln_relu_c(
    unsigned short* __restrict__ comb,
    const float* __restrict__ gn, const float* __restrict__ bn,
    const float* __restrict__ gt, const float* __restrict__ btp)
{
    const int b = blockIdx.x, t = threadIdx.x;
    const int r = b >> 1, half = b & 1;
    unsigned short* p = comb + (size_t)r * 2048 + half * 1024 + t * 4;
    ushort4 u = *(const ushort4*)p;
    const float x0 = bf2f(u.x), x1 = bf2f(u.y), x2 = bf2f(u.z), x3 = bf2f(u.w);
    float s1 = x0 + x1 + x2 + x3;
    float s2 = x0 * x0 + x1 * x1 + x2 * x2 + x3 * x3;
#pragma unroll
    for (int off = 32; off > 0; off >>= 1) {
        s1 += __shfl_down(s1, off);
        s2 += __shfl_down(s2, off);
    }
    __shared__ float red[8];
    const int wid = t >> 6;
    if ((t & 63) == 0) { red[wid] = s1; red[4 + wid] = s2; }
    __syncthreads();
    s1 = red[0] + red[1] + red[2] + red[3];
    s2 = red[4] + red[5] + red[6] + red[7];
    const float mean = s1 * (1.0f / 1024.0f);
    const float var = fmaxf(s2 * (1.0f / 1024.0f) - mean * mean, 0.0f);
    const float rstd = rsqrtf(var + 1e-5f);
    const float* G  = half ? gt : gn;
    const float* Be = half ? btp : bn;
    const float4 g  = ((const float4*)G)[t];
    const float4 be = ((const float4*)Be)[t];
    u.x = f2bf(fmaxf((x0 - mean) * rstd * g.x + be.x, 0.0f));
    u.y = f2bf(fmaxf((x1 - mean) * rstd * g.y + be.y, 0.0f));
    u.z = f2bf(fmaxf((x2 - mean) * rstd * g.z + be.z, 0.0f));
    u.w = f2bf(fmaxf((x3 - mean) * rstd * g.w + be.w, 0.0f));
    *(ushort4*)p = u;
}

// Fused: LN(1024)+ReLU on preln row (lang gamma/beta) -> gate dots -> sigmoid
// -> scale combined halves -> f32 outputs. One block per row.
__global__ __launch_bounds__(256) void ln_gate(
    const unsigned short* __restrict__ preln, const unsigned short* __restrict__ comb,
    const float* __restrict__ gg, const float* __restrict__ bgb,
    const float* __restrict__ Wg2, const float* __restrict__ bg2,
    const int* __restrict__ lang,
    float* __restrict__ outN, float* __restrict__ outT)
{
    const int r = blockIdx.x, t = threadIdx.x;
    const int l = lang[r >> 9];
    const ushort4 u = *(const ushort4*)(preln + (size_t)r * 1024 + t * 4);
    const float x0 = bf2f(u.x), x1 = bf2f(u.y), x2 = bf2f(u.z), x3 = bf2f(u.w);
    float s1 = x0 + x1 + x2 + x3;
    float s2 = x0 * x0 + x1 * x1 + x2 * x2 + x3 * x3;
#pragma unroll
    for (int off = 32; off > 0; off >>= 1) {
        s1 += __shfl_down(s1, off);
        s2 += __shfl_down(s2, off);
    }
    __shared__ float red[8];
    const int wid = t >> 6;
    if ((t & 63) == 0) { red[wid] = s1; red[4 + wid] = s2; }
    __syncthreads();
    s1 = red[0] + red[1] + red[2] + red[3];
    s2 = red[4] + red[5] + red[6] + red[7];
    const float mean = s1 * (1.0f / 1024.0f);
    const float var = fmaxf(s2 * (1.0f / 1024.0f) - mean * mean, 0.0f);
    const float rstd = rsqrtf(var + 1e-5f);
    const float4 g  = ((const float4*)(gg + l * 1024))[t];
    const float4 be = ((const float4*)(bgb + l * 1024))[t];
    const float h0 = fmaxf((x0 - mean) * rstd * g.x + be.x, 0.0f);
    const float h1 = fmaxf((x1 - mean) * rstd * g.y + be.y, 0.0f);
    const float h2 = fmaxf((x2 - mean) * rstd * g.z + be.z, 0.0f);
    const float h3 = fmaxf((x3 - mean) * rstd * g.w + be.w, 0.0f);
    const float4* W = (const float4*)(Wg2 + (size_t)l * 2048);
    const float4 wa = W[t * 2], wb = W[t * 2 + 1];
    float d0 = h0 * wa.x + h1 * wa.z + h2 * wb.x + h3 * wb.z;
    float d1 = h0 * wa.y + h1 * wa.w + h2 * wb.y + h3 * wb.w;
#pragma unroll
    for (int off = 32; off > 0; off >>= 1) {
        d0 += __shfl_down(d0, off);
        d1 += __shfl_down(d1, off);
    }
    __syncthreads();
    if ((t & 63) == 0) { red[wid] = d0; red[4 + wid] = d1; }
    __syncthreads();
    d0 = red[0] + red[1] + red[2] + red[3] + bg2[l * 2 + 0];
    d1 = red[4] + red[5] + red[6] + red[7] + bg2[l * 2 + 1];
    const float g0 = 1.0f / (1.0f + __expf(-d0));
    const float g1 = 1.0f / (1.0f + __expf(-d1));
    const ushort4 cn = *(const ushort4*)(comb + (size_t)r * 2048 + t * 4);
    const ushort4 ct = *(const ushort4*)(comb + (size_t)r * 2048 + 1024 + t * 4);
    float4 a, b;
    a.x = bf2f(cn.x) * g0; a.y = bf2f(cn.y) * g0; a.z = bf2f(cn.z) * g0; a.w = bf2f(cn.w) * g0;
    b.x = bf2f(ct.x) * g1; b.y = bf2f(ct.y) * g1; b.z = bf2f(ct.z) * g1; b.w = bf2f(ct.w) * g1;
    ((float4*)(outN + (size_t)r * 1024))[t] = a;
    ((float4*)(outT + (size_t)r * 1024))[t] = b;
}

extern "C" void kernel_launch(void* const* d_in, const int* in_sizes, int n_in,
                              void* d_out, int out_size, void* d_ws, size_t ws_size,
                              hipStream_t stream)
{
    const float* ner    = (const float*)d_in[0];
    const float* top    = (const float*)d_in[1];
    const int*   lang   = (const int*)d_in[2];
    const float* W_ner  = (const float*)d_in[3];
    const float* b_ner  = (const float*)d_in[4];
    const float* g_ner  = (const float*)d_in[5];
    const float* be_ner = (const float*)d_in[6];
    const float* W_top  = (const float*)d_in[7];
    const float* b_top  = (const float*)d_in[8];
    const float* g_top  = (const float*)d_in[9];
    const float* be_top = (const float*)d_in[10];
    const float* Wg1    = (const float*)d_in[11];
    const float* bg1    = (const float*)d_in[12];
    const float* gg     = (const float*)d_in[13];
    const float* bgb    = (const float*)d_in[14];
    const float* Wg2    = (const float*)d_in[15];
    const float* bg2    = (const float*)d_in[16];

    float* out  = (float*)d_out;
    float* outN = out;
    float* outT = out + 8388608;

    // ws layout: combined 32MB | actb 24MB (later preln2) | Wg1t 20MB
    char* ws = (char*)d_ws;
    unsigned short* combined = (unsigned short*)ws;
    unsigned short* actb     = (unsigned short*)(ws + 33554432);
    unsigned short* preln2   = (unsigned short*)(ws + 33554432);  // overlays actb (dead)
    unsigned short* Wg1t     = (unsigned short*)(ws + 58720256);
    unsigned short* W_nert   = (unsigned short*)outT;             // d_out scratch
    unsigned short* W_topt   = W_nert + 786432;

    // fused prep: W transposes (coalesced) + activation bf16 converts
    prep_all<<<9088, 256, 0, stream>>>(W_ner, W_nert, W_top, W_topt,
                                       Wg1, Wg1t, ner, top, actb);

    // merged shared-transform GEMM: [16384][768] -> combined pre-LN bf16
    gemm_w8<768, 0><<<dim3(8, 128), 512, 0, stream>>>(
        actb, W_nert, W_topt, b_ner, b_top, combined, nullptr);
    ln_relu_c<<<16384, 256, 0, stream>>>(combined, g_ner, be_ner, g_top, be_top);

    // gate GEMM (language-selected): combined @ Wg1t[l] -> preln2 bf16
    gemm_w8<2048, 1><<<dim3(8, 64), 512, 0, stream>>>(
        combined, Wg1t, nullptr, bg1, nullptr, preln2, lang);

    // fused LN2 + gate dots + sigmoid + output scaling
    ln_gate<<<8192, 256, 0, stream>>>(preln2, combined, gg, bgb, Wg2, bg2, lang, outN, outT);
}